// Round 1
// baseline (618.291 us; speedup 1.0000x reference)
//
#include <hip/hip_runtime.h>
#include <math.h>

#define F_DIM 128
#define H_DIM 128

__device__ __forceinline__ float sigmoidf_(float v) { return 1.f / (1.f + expf(-v)); }

// ---------- prep: sigmoid(feature_importance) ----------
__global__ void k_prep(const float* __restrict__ fi, float* __restrict__ sigf) {
    int j = threadIdx.x;
    if (j < 128) sigf[j] = sigmoidf_(fi[j]);
}

// ---------- build combined weight  Wfull[256][256] ----------
// cols 0..127   : c1 weights = 0.5*W_mean stacked twice (x half, mean half)
// cols 128..191 : W_ego (k<128 only)
// cols 192..255 : W_nb  (k>=128 only)
__global__ void k_wfull(const float* __restrict__ Wm, const float* __restrict__ We,
                        const float* __restrict__ Wn, float* __restrict__ Wfull) {
    int idx = blockIdx.x * 256 + threadIdx.x;  // 0..65535
    int k = idx >> 8, jj = idx & 255;
    float v;
    if (jj < 128) {
        v = 0.5f * Wm[(k & 127) * 128 + jj];
    } else {
        int j = jj - 128;
        if (j < 64) v = (k < 128) ? We[k * 64 + j] : 0.f;
        else        v = (k >= 128) ? Wn[(k - 128) * 64 + (j - 64)] : 0.f;
    }
    Wfull[idx] = v;
}

// ---------- degree count ----------
__global__ void k_deg(const int* __restrict__ src, int* __restrict__ deg, int E) {
    int e = blockIdx.x * blockDim.x + threadIdx.x;
    if (e < E) atomicAdd(&deg[src[e]], 1);
}

// ---------- scan (3 kernels) ----------
__global__ void k_scan1(const int* __restrict__ deg, int* __restrict__ bsum, int n) {
    __shared__ int lds[256];
    int i = blockIdx.x * 256 + threadIdx.x;
    lds[threadIdx.x] = (i < n) ? deg[i] : 0;
    __syncthreads();
    for (int s = 128; s > 0; s >>= 1) {
        if (threadIdx.x < s) lds[threadIdx.x] += lds[threadIdx.x + s];
        __syncthreads();
    }
    if (threadIdx.x == 0) bsum[blockIdx.x] = lds[0];
}

__global__ void k_scan2(const int* __restrict__ bsum, int* __restrict__ boff, int nb,
                        int* __restrict__ off, int n, int Etot) {
    __shared__ int lds[512];
    int t = threadIdx.x;
    int v = (t < nb) ? bsum[t] : 0;
    lds[t] = v;
    __syncthreads();
    for (int s = 1; s < 512; s <<= 1) {
        int add = (t >= s) ? lds[t - s] : 0;
        __syncthreads();
        lds[t] += add;
        __syncthreads();
    }
    if (t < nb) boff[t] = lds[t] - v;  // exclusive
    if (t == 0) off[n] = Etot;
}

__global__ void k_scan3(const int* __restrict__ deg, const int* __restrict__ boff,
                        int* __restrict__ off, int* __restrict__ pos, int n) {
    __shared__ int lds[256];
    int i = blockIdx.x * 256 + threadIdx.x;
    int v = (i < n) ? deg[i] : 0;
    lds[threadIdx.x] = v;
    __syncthreads();
    for (int s = 1; s < 256; s <<= 1) {
        int add = (threadIdx.x >= s) ? lds[threadIdx.x - s] : 0;
        __syncthreads();
        lds[threadIdx.x] += add;
        __syncthreads();
    }
    if (i < n) {
        int ex = boff[blockIdx.x] + lds[threadIdx.x] - v;
        off[i] = ex;
        pos[i] = ex;
    }
}

// ---------- CSR fill ----------
__global__ void k_fill(const int* __restrict__ src, const int* __restrict__ dst,
                       int* __restrict__ pos, int* __restrict__ csr, int E) {
    int e = blockIdx.x * blockDim.x + threadIdx.x;
    if (e < E) {
        int s = src[e];
        int p = atomicAdd(&pos[s], 1);
        csr[p] = dst[e];
    }
}

// ---------- aggregate: mean_neighbor + dilution gate (fused), wave per node ----------
__global__ __launch_bounds__(256) void k_agg(
    const float* __restrict__ x, const float* __restrict__ sigf,
    const int* __restrict__ off, const int* __restrict__ csr,
    const float* __restrict__ gw, const float* __restrict__ gb,
    float* __restrict__ mean, float* __restrict__ gate, int n) {
    int wave = (blockIdx.x * blockDim.x + threadIdx.x) >> 6;
    int lane = threadIdx.x & 63;
    if (wave >= n) return;
    int i = wave;
    int c0 = lane * 2;
    float sf0 = sigf[c0], sf1 = sigf[c0 + 1];
    int beg = off[i], end = off[i + 1];
    float s0 = 0.f, s1 = 0.f;
    for (int e = beg; e < end; ++e) {
        int d = csr[e];
        float2 v = *(const float2*)&x[(size_t)d * 128 + c0];
        s0 += v.x;
        s1 += v.y;
    }
    // gated-x sum = sigf * sum(x)
    s0 *= sf0; s1 *= sf1;
    int dg = end - beg;
    float inv = 1.f / fmaxf((float)dg, 1.f);
    float m0 = s0 * inv, m1 = s1 * inv;
    *(float2*)&mean[(size_t)i * 128 + c0] = make_float2(m0, m1);
    float2 xv = *(const float2*)&x[(size_t)i * 128 + c0];
    float x0 = xv.x * sf0, x1 = xv.y * sf1;
    float px = x0 * x0 + x1 * x1;
    float pm = m0 * m0 + m1 * m1;
    float pc = x0 * m0 + x1 * m1;
    for (int s = 32; s > 0; s >>= 1) {
        px += __shfl_xor(px, s, 64);
        pm += __shfl_xor(pm, s, 64);
        pc += __shfl_xor(pc, s, 64);
    }
    if (lane == 0) {
        float nx = fmaxf(sqrtf(px), 1e-12f), nm = fmaxf(sqrtf(pm), 1e-12f);
        float sim = pc / (nx * nm);
        if (dg <= 0) sim = 1.f;
        float delta = sigmoidf_((float)dg * (1.f - sim) * 0.1f - 0.5f);
        float g = sigmoidf_(gw[0] * delta + gb[0]);
        gate[i] = g;
    }
}

// ---------- GEMM: h_pre = gatecombine( [x_g|mean] @ Wfull ) ----------
#define TM 32
__global__ __launch_bounds__(256) void k_gemm(
    const float* __restrict__ x, const float* __restrict__ sigf,
    const float* __restrict__ mean, const float* __restrict__ Wfull,
    const float* __restrict__ b_mean, const float* __restrict__ b_ego,
    const float* __restrict__ b_nb, const float* __restrict__ gate,
    float* __restrict__ h, int n) {
    __shared__ float z[TM][256];
    int tid = threadIdx.x;
    int row0 = blockIdx.x * TM;
    // stage z = [x*sigf | mean]
    for (int q = tid; q < TM * 64; q += 256) {
        int r = q >> 6;
        int c4 = (q & 63) * 4;
        int grow = row0 + r;
        float4 v;
        if (grow < n) {
            if (c4 < 128) {
                v = *(const float4*)&x[(size_t)grow * 128 + c4];
                v.x *= sigf[c4]; v.y *= sigf[c4 + 1]; v.z *= sigf[c4 + 2]; v.w *= sigf[c4 + 3];
            } else {
                v = *(const float4*)&mean[(size_t)grow * 128 + (c4 - 128)];
            }
        } else {
            v = make_float4(0.f, 0.f, 0.f, 0.f);
        }
        *(float4*)&z[r][c4] = v;
    }
    __syncthreads();

    int jg = tid & 63, j0 = jg * 4;
    int rg = tid >> 6, r0 = rg * 8;
    float acc[8][4];
#pragma unroll
    for (int a = 0; a < 8; a++)
#pragma unroll
        for (int b = 0; b < 4; b++) acc[a][b] = 0.f;

    for (int k = 0; k < 256; k += 4) {
        float4 w0 = *(const float4*)&Wfull[(size_t)(k + 0) * 256 + j0];
        float4 w1 = *(const float4*)&Wfull[(size_t)(k + 1) * 256 + j0];
        float4 w2 = *(const float4*)&Wfull[(size_t)(k + 2) * 256 + j0];
        float4 w3 = *(const float4*)&Wfull[(size_t)(k + 3) * 256 + j0];
#pragma unroll
        for (int r = 0; r < 8; r++) {
            float4 zv = *(const float4*)&z[r0 + r][k];
            acc[r][0] = fmaf(zv.x, w0.x, fmaf(zv.y, w1.x, fmaf(zv.z, w2.x, fmaf(zv.w, w3.x, acc[r][0]))));
            acc[r][1] = fmaf(zv.x, w0.y, fmaf(zv.y, w1.y, fmaf(zv.z, w2.y, fmaf(zv.w, w3.y, acc[r][1]))));
            acc[r][2] = fmaf(zv.x, w0.z, fmaf(zv.y, w1.z, fmaf(zv.z, w2.z, fmaf(zv.w, w3.z, acc[r][2]))));
            acc[r][3] = fmaf(zv.x, w0.w, fmaf(zv.y, w1.w, fmaf(zv.z, w2.w, fmaf(zv.w, w3.w, acc[r][3]))));
        }
    }
    __syncthreads();
    // write y into z (reuse)
#pragma unroll
    for (int r = 0; r < 8; r++) {
        *(float4*)&z[r0 + r][j0] = make_float4(acc[r][0], acc[r][1], acc[r][2], acc[r][3]);
    }
    __syncthreads();
    // epilogue: gate combine
    int j = tid & 127;
    int rh = tid >> 7;  // 0..1
    float bm = b_mean[j];
    float bc = (j < 64) ? b_ego[j] : b_nb[j - 64];
    for (int r = 0; r < 16; r++) {
        int row = rh * 16 + r;
        int grow = row0 + row;
        if (grow >= n) break;
        float g = gate[grow];
        float c1 = z[row][j] + bm;
        float cc = z[row][128 + j] + bc;
        h[(size_t)grow * 128 + j] = (1.f - g) * c1 + g * cc;
    }
}

// ---------- BN stats reduce ----------
__global__ __launch_bounds__(256) void k_bnred(const float* __restrict__ h,
                                               float* __restrict__ stats, int n) {
    int col = threadIdx.x & 127;
    int sub = threadIdx.x >> 7;
    float s = 0.f, ss = 0.f;
    for (int row = blockIdx.x * 2 + sub; row < n; row += gridDim.x * 2) {
        float v = h[(size_t)row * 128 + col];
        s += v;
        ss += v * v;
    }
    __shared__ float l1[256], l2[256];
    l1[threadIdx.x] = s;
    l2[threadIdx.x] = ss;
    __syncthreads();
    if (threadIdx.x < 128) {
        atomicAdd(&stats[col], l1[threadIdx.x] + l1[threadIdx.x + 128]);
        atomicAdd(&stats[128 + col], l2[threadIdx.x] + l2[threadIdx.x + 128]);
    }
}

__global__ void k_bnfin(const float* __restrict__ stats, const float* __restrict__ gamma,
                        const float* __restrict__ beta, float* __restrict__ sshift, int n) {
    int j = threadIdx.x;
    if (j < 128) {
        float invn = 1.f / (float)n;
        float mu = stats[j] * invn;
        float var = stats[128 + j] * invn - mu * mu;
        float rstd = 1.f / sqrtf(var + 1e-5f);
        float sc = gamma[j] * rstd;
        sshift[j] = sc;
        sshift[128 + j] = beta[j] - sc * mu;
    }
}

// ---------- normalize+relu+h@W_gcn fused, wave per row ----------
__global__ __launch_bounds__(256) void k_hw(
    const float* __restrict__ h, const float* __restrict__ sshift,
    const float* __restrict__ Wg, const int* __restrict__ deg,
    float* __restrict__ hw, float* __restrict__ dinv, int n) {
    int wave = (blockIdx.x * blockDim.x + threadIdx.x) >> 6;
    int lane = threadIdx.x & 63;
    if (wave >= n) return;
    int i = wave;
    int c0 = lane * 2;
    float2 hv = *(const float2*)&h[(size_t)i * 128 + c0];
    float h0 = fmaxf(hv.x * sshift[c0] + sshift[128 + c0], 0.f);
    float h1 = fmaxf(hv.y * sshift[c0 + 1] + sshift[128 + c0 + 1], 0.f);
    float p0 = h0 * Wg[c0 * 2 + 0] + h1 * Wg[(c0 + 1) * 2 + 0];
    float p1 = h0 * Wg[c0 * 2 + 1] + h1 * Wg[(c0 + 1) * 2 + 1];
    for (int s = 32; s > 0; s >>= 1) {
        p0 += __shfl_xor(p0, s, 64);
        p1 += __shfl_xor(p1, s, 64);
    }
    if (lane == 0) {
        hw[(size_t)i * 2 + 0] = p0;
        hw[(size_t)i * 2 + 1] = p1;
        dinv[i] = rsqrtf((float)(deg[i] + 1));
    }
}

// ---------- GCN scatter via CSR, 16 lanes per node ----------
__global__ __launch_bounds__(256) void k_out(
    const int* __restrict__ off, const int* __restrict__ csr,
    const float* __restrict__ dinv, const float* __restrict__ hw,
    const float* __restrict__ bg, float* __restrict__ out, int n) {
    int t = blockIdx.x * blockDim.x + threadIdx.x;
    int node = t >> 4;
    int l = t & 15;
    if (node >= n) return;
    float s0 = 0.f, s1 = 0.f;
    int beg = off[node], end = off[node + 1];
    for (int e = beg + l; e < end; e += 16) {
        int d = csr[e];
        float w = dinv[d];
        float2 hv = *(const float2*)&hw[(size_t)d * 2];
        s0 += w * hv.x;
        s1 += w * hv.y;
    }
    for (int m = 8; m > 0; m >>= 1) {
        s0 += __shfl_xor(s0, m, 16);
        s1 += __shfl_xor(s1, m, 16);
    }
    if (l == 0) {
        float di = dinv[node];
        float2 hv = *(const float2*)&hw[(size_t)node * 2];
        out[(size_t)node * 2 + 0] = bg[0] + di * (s0 + di * hv.x);
        out[(size_t)node * 2 + 1] = bg[1] + di * (s1 + di * hv.y);
    }
}

extern "C" void kernel_launch(void* const* d_in, const int* in_sizes, int n_in,
                              void* d_out, int out_size, void* d_ws, size_t ws_size,
                              hipStream_t stream) {
    const float* x     = (const float*)d_in[0];
    const int*   ei    = (const int*)d_in[1];
    const float* fi    = (const float*)d_in[2];
    const float* Wm    = (const float*)d_in[3];
    const float* bm    = (const float*)d_in[4];
    const float* We    = (const float*)d_in[5];
    const float* be    = (const float*)d_in[6];
    const float* Wn    = (const float*)d_in[7];
    const float* bn    = (const float*)d_in[8];
    const float* gw    = (const float*)d_in[9];
    const float* gb    = (const float*)d_in[10];
    const float* gamma = (const float*)d_in[11];
    const float* beta  = (const float*)d_in[12];
    const float* Wg    = (const float*)d_in[13];
    const float* bg    = (const float*)d_in[14];

    int n = in_sizes[0] / 128;
    int E = in_sizes[1] / 2;
    const int* src = ei;
    const int* dst = ei + E;

    char* p = (char*)d_ws;
    auto alloc = [&](size_t bytes) {
        void* r = (void*)p;
        p += (bytes + 255) & ~(size_t)255;
        return r;
    };
    float* mean   = (float*)alloc((size_t)n * 128 * 4);
    float* h      = (float*)alloc((size_t)n * 128 * 4);
    float* Wfull  = (float*)alloc(256 * 256 * 4);
    int*   deg    = (int*)alloc((size_t)n * 4);
    int*   off    = (int*)alloc((size_t)(n + 1) * 4);
    int*   pos    = (int*)alloc((size_t)(n + 1) * 4);
    int*   csr    = (int*)alloc((size_t)E * 4);
    int*   bsum   = (int*)alloc(512 * 4);
    int*   boff   = (int*)alloc(512 * 4);
    float* gate   = (float*)alloc((size_t)n * 4);
    float* stats  = (float*)alloc(256 * 4);
    float* sshift = (float*)alloc(256 * 4);
    float* dinv   = (float*)alloc((size_t)n * 4);
    float* hwbuf  = (float*)alloc((size_t)n * 2 * 4);
    float* sigf   = (float*)alloc(128 * 4);

    hipMemsetAsync(deg, 0, (size_t)n * 4, stream);
    hipMemsetAsync(stats, 0, 256 * 4, stream);

    k_prep<<<1, 128, 0, stream>>>(fi, sigf);
    k_wfull<<<256, 256, 0, stream>>>(Wm, We, Wn, Wfull);
    k_deg<<<(E + 255) / 256, 256, 0, stream>>>(src, deg, E);

    int nb = (n + 255) / 256;
    k_scan1<<<nb, 256, 0, stream>>>(deg, bsum, n);
    k_scan2<<<1, 512, 0, stream>>>(bsum, boff, nb, off, n, E);
    k_scan3<<<nb, 256, 0, stream>>>(deg, boff, off, pos, n);
    k_fill<<<(E + 255) / 256, 256, 0, stream>>>(src, dst, pos, csr, E);

    k_agg<<<(n + 3) / 4, 256, 0, stream>>>(x, sigf, off, csr, gw, gb, mean, gate, n);
    k_gemm<<<(n + TM - 1) / TM, 256, 0, stream>>>(x, sigf, mean, Wfull, bm, be, bn, gate, h, n);
    k_bnred<<<512, 256, 0, stream>>>(h, stats, n);
    k_bnfin<<<1, 128, 0, stream>>>(stats, gamma, beta, sshift, n);
    k_hw<<<(n + 3) / 4, 256, 0, stream>>>(h, sshift, Wg, deg, hwbuf, dinv, n);
    k_out<<<(n + 15) / 16, 256, 0, stream>>>(off, csr, dinv, hwbuf, bg, (float*)d_out, n);
}

// Round 2
// 419.259 us; speedup vs baseline: 1.4747x; 1.4747x over previous
//
#include <hip/hip_runtime.h>
#include <hip/hip_bf16.h>
#include <math.h>

typedef __attribute__((ext_vector_type(8))) short bfx8;
typedef __attribute__((ext_vector_type(4))) float fx4;

__device__ __forceinline__ float sigmoidf_(float v) { return 1.f / (1.f + expf(-v)); }
__device__ __forceinline__ float blo(unsigned u) { return __uint_as_float(u << 16); }
__device__ __forceinline__ float bhi(unsigned u) { return __uint_as_float(u & 0xffff0000u); }
__device__ __forceinline__ unsigned short f2b(float v) {
    __hip_bfloat16 hb = __float2bfloat16(v);
    return *(unsigned short*)&hb;
}

// ---------- prep: sigmoid(feature_importance) ----------
__global__ void k_prep(const float* __restrict__ fi, float* __restrict__ sigf) {
    int j = threadIdx.x;
    if (j < 128) sigf[j] = sigmoidf_(fi[j]);
}

// ---------- build combined transposed weight WfT[col][k], bf16 ----------
// out col 0..127  : y1 = 0.5*W_mean (k<128: x-half, k>=128: mean-half, same W)
// out col 128..191: y2 ego  = W_ego (k<128 only)
// out col 192..255: y2 nb   = W_nb  (k>=128 only)
__global__ void k_wfullT(const float* __restrict__ Wm, const float* __restrict__ We,
                         const float* __restrict__ Wn, unsigned short* __restrict__ WfT) {
    int idx = blockIdx.x * 256 + threadIdx.x;  // = col*256 + k
    int col = idx >> 8, k = idx & 255;
    float v;
    if (col < 128) {
        v = 0.5f * Wm[(k & 127) * 128 + col];
    } else {
        int j = col - 128;
        if (j < 64) v = (k < 128) ? We[k * 64 + j] : 0.f;
        else        v = (k >= 128) ? Wn[(k - 128) * 64 + (j - 64)] : 0.f;
    }
    WfT[idx] = f2b(v);
}

// ---------- convert gated x to bf16: xg = bf16(x * sigf) ----------
__global__ __launch_bounds__(256) void k_conv(const float* __restrict__ x,
                                              const float* __restrict__ sigf,
                                              unsigned short* __restrict__ xg,
                                              long long total) {
    long long t = (long long)blockIdx.x * 256 + threadIdx.x;
    long long base = t * 8;
    if (base >= total) return;
    int c = (int)(base & 127);
    float4 a = *(const float4*)&x[base];
    float4 b = *(const float4*)&x[base + 4];
    unsigned short u[8];
    u[0] = f2b(a.x * sigf[c + 0]); u[1] = f2b(a.y * sigf[c + 1]);
    u[2] = f2b(a.z * sigf[c + 2]); u[3] = f2b(a.w * sigf[c + 3]);
    u[4] = f2b(b.x * sigf[c + 4]); u[5] = f2b(b.y * sigf[c + 5]);
    u[6] = f2b(b.z * sigf[c + 6]); u[7] = f2b(b.w * sigf[c + 7]);
    *(uint4*)&xg[base] = *(uint4*)u;
}

// ---------- degree count ----------
__global__ void k_deg(const int* __restrict__ src, int* __restrict__ deg, int E) {
    int e = blockIdx.x * blockDim.x + threadIdx.x;
    if (e < E) atomicAdd(&deg[src[e]], 1);
}

// ---------- scan (3 kernels) ----------
__global__ void k_scan1(const int* __restrict__ deg, int* __restrict__ bsum, int n) {
    __shared__ int lds[256];
    int i = blockIdx.x * 256 + threadIdx.x;
    lds[threadIdx.x] = (i < n) ? deg[i] : 0;
    __syncthreads();
    for (int s = 128; s > 0; s >>= 1) {
        if (threadIdx.x < s) lds[threadIdx.x] += lds[threadIdx.x + s];
        __syncthreads();
    }
    if (threadIdx.x == 0) bsum[blockIdx.x] = lds[0];
}

__global__ void k_scan2(const int* __restrict__ bsum, int* __restrict__ boff, int nb,
                        int* __restrict__ off, int n, int Etot) {
    __shared__ int lds[512];
    int t = threadIdx.x;
    int v = (t < nb) ? bsum[t] : 0;
    lds[t] = v;
    __syncthreads();
    for (int s = 1; s < 512; s <<= 1) {
        int add = (t >= s) ? lds[t - s] : 0;
        __syncthreads();
        lds[t] += add;
        __syncthreads();
    }
    if (t < nb) boff[t] = lds[t] - v;  // exclusive
    if (t == 0) off[n] = Etot;
}

__global__ void k_scan3(const int* __restrict__ deg, const int* __restrict__ boff,
                        int* __restrict__ off, int* __restrict__ pos, int n) {
    __shared__ int lds[256];
    int i = blockIdx.x * 256 + threadIdx.x;
    int v = (i < n) ? deg[i] : 0;
    lds[threadIdx.x] = v;
    __syncthreads();
    for (int s = 1; s < 256; s <<= 1) {
        int add = (threadIdx.x >= s) ? lds[threadIdx.x - s] : 0;
        __syncthreads();
        lds[threadIdx.x] += add;
        __syncthreads();
    }
    if (i < n) {
        int ex = boff[blockIdx.x] + lds[threadIdx.x] - v;
        off[i] = ex;
        pos[i] = ex;
    }
}

// ---------- CSR fill ----------
__global__ void k_fill(const int* __restrict__ src, const int* __restrict__ dst,
                       int* __restrict__ pos, int* __restrict__ csr, int E) {
    int e = blockIdx.x * blockDim.x + threadIdx.x;
    if (e < E) {
        int s = src[e];
        int p = atomicAdd(&pos[s], 1);
        csr[p] = dst[e];
    }
}

// ---------- aggregate (bf16 gather): mean_neighbor + dilution gate ----------
__global__ __launch_bounds__(256) void k_agg(
    const unsigned short* __restrict__ xg,
    const int* __restrict__ off, const int* __restrict__ csr,
    const float* __restrict__ gw, const float* __restrict__ gb,
    unsigned short* __restrict__ meanb, float* __restrict__ gate, int n) {
    int wave = (blockIdx.x * blockDim.x + threadIdx.x) >> 6;
    int lane = threadIdx.x & 63;
    if (wave >= n) return;
    int i = wave;
    int c0 = lane * 2;
    int beg = off[i], end = off[i + 1];
    float s0 = 0.f, s1 = 0.f;
    int e = beg;
    for (; e + 4 <= end; e += 4) {
        int d0 = csr[e], d1 = csr[e + 1], d2 = csr[e + 2], d3 = csr[e + 3];
        unsigned u0 = *(const unsigned*)&xg[(size_t)d0 * 128 + c0];
        unsigned u1 = *(const unsigned*)&xg[(size_t)d1 * 128 + c0];
        unsigned u2 = *(const unsigned*)&xg[(size_t)d2 * 128 + c0];
        unsigned u3 = *(const unsigned*)&xg[(size_t)d3 * 128 + c0];
        s0 += blo(u0) + blo(u1) + blo(u2) + blo(u3);
        s1 += bhi(u0) + bhi(u1) + bhi(u2) + bhi(u3);
    }
    for (; e < end; ++e) {
        int d = csr[e];
        unsigned u = *(const unsigned*)&xg[(size_t)d * 128 + c0];
        s0 += blo(u);
        s1 += bhi(u);
    }
    int dg = end - beg;
    float inv = 1.f / fmaxf((float)dg, 1.f);
    float m0 = s0 * inv, m1 = s1 * inv;
    unsigned packed = (unsigned)f2b(m0) | ((unsigned)f2b(m1) << 16);
    *(unsigned*)&meanb[(size_t)i * 128 + c0] = packed;
    unsigned ux = *(const unsigned*)&xg[(size_t)i * 128 + c0];
    float x0 = blo(ux), x1 = bhi(ux);
    float px = x0 * x0 + x1 * x1;
    float pm = m0 * m0 + m1 * m1;
    float pc = x0 * m0 + x1 * m1;
    for (int s = 32; s > 0; s >>= 1) {
        px += __shfl_xor(px, s, 64);
        pm += __shfl_xor(pm, s, 64);
        pc += __shfl_xor(pc, s, 64);
    }
    if (lane == 0) {
        float nx = fmaxf(sqrtf(px), 1e-12f), nm = fmaxf(sqrtf(pm), 1e-12f);
        float sim = pc / (nx * nm);
        if (dg <= 0) sim = 1.f;
        float delta = sigmoidf_((float)dg * (1.f - sim) * 0.1f - 0.5f);
        float g = sigmoidf_(gw[0] * delta + gb[0]);
        gate[i] = g;
    }
}

// ---------- MFMA GEMM: h = gate-combine([xg|mean] @ Wfull), fused BN stats ----------
// block = 256 thr = 4 waves, tile 64 rows x 256 cols.
// wave w covers cols {32w..32w+31} (y1) and {128+32w..128+32w+31} (y2) so the
// gate combine is register-local. No LDS.
__global__ __launch_bounds__(256) void k_gemm2(
    const unsigned short* __restrict__ xg, const unsigned short* __restrict__ meanb,
    const unsigned short* __restrict__ WfT,
    const float* __restrict__ b_mean, const float* __restrict__ b_ego,
    const float* __restrict__ b_nb, const float* __restrict__ gate,
    float* __restrict__ h, float* __restrict__ stats, int n) {
    int lane = threadIdx.x & 63;
    int w = threadIdx.x >> 6;
    int row0 = blockIdx.x * 64;
    int rl = lane & 15;
    int kg = lane >> 4;

    fx4 acc[4][4];
#pragma unroll
    for (int a = 0; a < 4; a++)
#pragma unroll
        for (int b = 0; b < 4; b++) acc[a][b] = (fx4){0.f, 0.f, 0.f, 0.f};

    int cb0 = 32 * w;
#pragma unroll
    for (int ks = 0; ks < 8; ++ks) {
        int k = ks * 32 + kg * 8;
        bfx8 af[4];
#pragma unroll
        for (int fa = 0; fa < 4; ++fa) {
            int grow = row0 + 16 * fa + rl;
            if (grow >= n) grow = n - 1;
            const unsigned short* src = (k < 128)
                ? &xg[(size_t)grow * 128 + k]
                : &meanb[(size_t)grow * 128 + (k - 128)];
            af[fa] = *(const bfx8*)src;
        }
        bfx8 bf[4];
#pragma unroll
        for (int fb = 0; fb < 4; ++fb) {
            int col = cb0 + 16 * (fb & 1) + 128 * (fb >> 1) + rl;
            bf[fb] = *(const bfx8*)&WfT[(size_t)col * 256 + k];
        }
#pragma unroll
        for (int fa = 0; fa < 4; ++fa)
#pragma unroll
            for (int fb = 0; fb < 4; ++fb)
                acc[fa][fb] = __builtin_amdgcn_mfma_f32_16x16x32_bf16(af[fa], bf[fb], acc[fa][fb], 0, 0, 0);
    }

    // epilogue: gate combine + h write + BN stats partials
    int j0 = cb0 + rl;
    int j1 = j0 + 16;
    float bm0 = b_mean[j0], bm1 = b_mean[j1];
    float bc0 = (j0 < 64) ? b_ego[j0] : b_nb[j0 - 64];
    float bc1 = (j1 < 64) ? b_ego[j1] : b_nb[j1 - 64];
    float cs0 = 0.f, cs1 = 0.f, cq0 = 0.f, cq1 = 0.f;
#pragma unroll
    for (int fa = 0; fa < 4; ++fa) {
#pragma unroll
        for (int r = 0; r < 4; ++r) {
            int grow = row0 + 16 * fa + 4 * kg + r;
            if (grow < n) {
                float g = gate[grow];
                float h0 = (1.f - g) * (acc[fa][0][r] + bm0) + g * (acc[fa][2][r] + bc0);
                float h1 = (1.f - g) * (acc[fa][1][r] + bm1) + g * (acc[fa][3][r] + bc1);
                h[(size_t)grow * 128 + j0] = h0;
                h[(size_t)grow * 128 + j1] = h1;
                cs0 += h0; cq0 += h0 * h0;
                cs1 += h1; cq1 += h1 * h1;
            }
        }
    }
    cs0 += __shfl_xor(cs0, 16, 64); cs0 += __shfl_xor(cs0, 32, 64);
    cq0 += __shfl_xor(cq0, 16, 64); cq0 += __shfl_xor(cq0, 32, 64);
    cs1 += __shfl_xor(cs1, 16, 64); cs1 += __shfl_xor(cs1, 32, 64);
    cq1 += __shfl_xor(cq1, 16, 64); cq1 += __shfl_xor(cq1, 32, 64);
    if (lane < 16) {
        atomicAdd(&stats[j0], cs0);
        atomicAdd(&stats[128 + j0], cq0);
        atomicAdd(&stats[j1], cs1);
        atomicAdd(&stats[128 + j1], cq1);
    }
}

// ---------- BN finalize ----------
__global__ void k_bnfin(const float* __restrict__ stats, const float* __restrict__ gamma,
                        const float* __restrict__ beta, float* __restrict__ sshift, int n) {
    int j = threadIdx.x;
    if (j < 128) {
        float invn = 1.f / (float)n;
        float mu = stats[j] * invn;
        float var = stats[128 + j] * invn - mu * mu;
        float rstd = 1.f / sqrtf(var + 1e-5f);
        float sc = gamma[j] * rstd;
        sshift[j] = sc;
        sshift[128 + j] = beta[j] - sc * mu;
    }
}

// ---------- normalize+relu+h@W_gcn fused, wave per row ----------
__global__ __launch_bounds__(256) void k_hw(
    const float* __restrict__ h, const float* __restrict__ sshift,
    const float* __restrict__ Wg, const int* __restrict__ deg,
    float* __restrict__ hw, float* __restrict__ dinv, int n) {
    int wave = (blockIdx.x * blockDim.x + threadIdx.x) >> 6;
    int lane = threadIdx.x & 63;
    if (wave >= n) return;
    int i = wave;
    int c0 = lane * 2;
    float2 hv = *(const float2*)&h[(size_t)i * 128 + c0];
    float h0 = fmaxf(hv.x * sshift[c0] + sshift[128 + c0], 0.f);
    float h1 = fmaxf(hv.y * sshift[c0 + 1] + sshift[128 + c0 + 1], 0.f);
    float p0 = h0 * Wg[c0 * 2 + 0] + h1 * Wg[(c0 + 1) * 2 + 0];
    float p1 = h0 * Wg[c0 * 2 + 1] + h1 * Wg[(c0 + 1) * 2 + 1];
    for (int s = 32; s > 0; s >>= 1) {
        p0 += __shfl_xor(p0, s, 64);
        p1 += __shfl_xor(p1, s, 64);
    }
    if (lane == 0) {
        hw[(size_t)i * 2 + 0] = p0;
        hw[(size_t)i * 2 + 1] = p1;
        dinv[i] = rsqrtf((float)(deg[i] + 1));
    }
}

// ---------- GCN scatter via CSR, 16 lanes per node ----------
__global__ __launch_bounds__(256) void k_out(
    const int* __restrict__ off, const int* __restrict__ csr,
    const float* __restrict__ dinv, const float* __restrict__ hw,
    const float* __restrict__ bg, float* __restrict__ out, int n) {
    int t = blockIdx.x * blockDim.x + threadIdx.x;
    int node = t >> 4;
    int l = t & 15;
    if (node >= n) return;
    float s0 = 0.f, s1 = 0.f;
    int beg = off[node], end = off[node + 1];
    for (int e = beg + l; e < end; e += 16) {
        int d = csr[e];
        float wgt = dinv[d];
        float2 hv = *(const float2*)&hw[(size_t)d * 2];
        s0 += wgt * hv.x;
        s1 += wgt * hv.y;
    }
    for (int m = 8; m > 0; m >>= 1) {
        s0 += __shfl_xor(s0, m, 16);
        s1 += __shfl_xor(s1, m, 16);
    }
    if (l == 0) {
        float di = dinv[node];
        float2 hv = *(const float2*)&hw[(size_t)node * 2];
        out[(size_t)node * 2 + 0] = bg[0] + di * (s0 + di * hv.x);
        out[(size_t)node * 2 + 1] = bg[1] + di * (s1 + di * hv.y);
    }
}

extern "C" void kernel_launch(void* const* d_in, const int* in_sizes, int n_in,
                              void* d_out, int out_size, void* d_ws, size_t ws_size,
                              hipStream_t stream) {
    const float* x     = (const float*)d_in[0];
    const int*   ei    = (const int*)d_in[1];
    const float* fi    = (const float*)d_in[2];
    const float* Wm    = (const float*)d_in[3];
    const float* bm    = (const float*)d_in[4];
    const float* We    = (const float*)d_in[5];
    const float* be    = (const float*)d_in[6];
    const float* Wn    = (const float*)d_in[7];
    const float* bn    = (const float*)d_in[8];
    const float* gw    = (const float*)d_in[9];
    const float* gb    = (const float*)d_in[10];
    const float* gamma = (const float*)d_in[11];
    const float* beta  = (const float*)d_in[12];
    const float* Wg    = (const float*)d_in[13];
    const float* bg    = (const float*)d_in[14];

    int n = in_sizes[0] / 128;
    int E = in_sizes[1] / 2;
    const int* src = ei;
    const int* dst = ei + E;

    char* p = (char*)d_ws;
    auto alloc = [&](size_t bytes) {
        void* r = (void*)p;
        p += (bytes + 255) & ~(size_t)255;
        return r;
    };
    unsigned short* xg    = (unsigned short*)alloc((size_t)n * 128 * 2);
    unsigned short* meanb = (unsigned short*)alloc((size_t)n * 128 * 2);
    float*          h     = (float*)alloc((size_t)n * 128 * 4);
    unsigned short* WfT   = (unsigned short*)alloc(256 * 256 * 2);
    int*   deg    = (int*)alloc((size_t)n * 4);
    int*   off    = (int*)alloc((size_t)(n + 1) * 4);
    int*   pos    = (int*)alloc((size_t)(n + 1) * 4);
    int*   csr    = (int*)alloc((size_t)E * 4);
    int*   bsum   = (int*)alloc(512 * 4);
    int*   boff   = (int*)alloc(512 * 4);
    float* gate   = (float*)alloc((size_t)n * 4);
    float* stats  = (float*)alloc(256 * 4);
    float* sshift = (float*)alloc(256 * 4);
    float* dinv   = (float*)alloc((size_t)n * 4);
    float* hwbuf  = (float*)alloc((size_t)n * 2 * 4);
    float* sigf   = (float*)alloc(128 * 4);

    hipMemsetAsync(deg, 0, (size_t)n * 4, stream);
    hipMemsetAsync(stats, 0, 256 * 4, stream);

    k_prep<<<1, 128, 0, stream>>>(fi, sigf);
    k_wfullT<<<256, 256, 0, stream>>>(Wm, We, Wn, WfT);

    long long total = (long long)n * 128;
    int convBlocks = (int)((total / 8 + 255) / 256);
    k_conv<<<convBlocks, 256, 0, stream>>>(x, sigf, xg, total);

    k_deg<<<(E + 255) / 256, 256, 0, stream>>>(src, deg, E);

    int nb = (n + 255) / 256;
    k_scan1<<<nb, 256, 0, stream>>>(deg, bsum, n);
    k_scan2<<<1, 512, 0, stream>>>(bsum, boff, nb, off, n, E);
    k_scan3<<<nb, 256, 0, stream>>>(deg, boff, off, pos, n);
    k_fill<<<(E + 255) / 256, 256, 0, stream>>>(src, dst, pos, csr, E);

    k_agg<<<(n + 3) / 4, 256, 0, stream>>>(xg, off, csr, gw, gb, meanb, gate, n);
    k_gemm2<<<(n + 63) / 64, 256, 0, stream>>>(xg, meanb, WfT, bm, be, bn, gate, h, stats, n);
    k_bnfin<<<1, 128, 0, stream>>>(stats, gamma, beta, sshift, n);
    k_hw<<<(n + 3) / 4, 256, 0, stream>>>(h, sshift, Wg, deg, hwbuf, dinv, n);
    k_out<<<(n + 15) / 16, 256, 0, stream>>>(off, csr, dinv, hwbuf, bg, (float*)d_out, n);
}

// Round 3
// 371.863 us; speedup vs baseline: 1.6627x; 1.1275x over previous
//
#include <hip/hip_runtime.h>
#include <hip/hip_bf16.h>
#include <math.h>

typedef __attribute__((ext_vector_type(8))) short bfx8;
typedef __attribute__((ext_vector_type(4))) float fx4;

__device__ __forceinline__ float sigmoidf_(float v) { return 1.f / (1.f + expf(-v)); }
__device__ __forceinline__ float blo(unsigned u) { return __uint_as_float(u << 16); }
__device__ __forceinline__ float bhi(unsigned u) { return __uint_as_float(u & 0xffff0000u); }
__device__ __forceinline__ unsigned short f2b(float v) {
    __hip_bfloat16 hb = __float2bfloat16(v);
    return *(unsigned short*)&hb;
}

// ---------- prep: sigmoid(feature_importance) ----------
__global__ void k_prep(const float* __restrict__ fi, float* __restrict__ sigf) {
    int j = threadIdx.x;
    if (j < 128) sigf[j] = sigmoidf_(fi[j]);
}

// ---------- build combined transposed weight WfT[col][k], bf16 ----------
__global__ void k_wfullT(const float* __restrict__ Wm, const float* __restrict__ We,
                         const float* __restrict__ Wn, unsigned short* __restrict__ WfT) {
    int idx = blockIdx.x * 256 + threadIdx.x;  // = col*256 + k
    int col = idx >> 8, k = idx & 255;
    float v;
    if (col < 128) {
        v = 0.5f * Wm[(k & 127) * 128 + col];
    } else {
        int j = col - 128;
        if (j < 64) v = (k < 128) ? We[k * 64 + j] : 0.f;
        else        v = (k >= 128) ? Wn[(k - 128) * 64 + (j - 64)] : 0.f;
    }
    WfT[idx] = f2b(v);
}

// ---------- convert gated x to bf16: xg = bf16(x * sigf) ----------
__global__ __launch_bounds__(256) void k_conv(const float* __restrict__ x,
                                              const float* __restrict__ sigf,
                                              unsigned short* __restrict__ xg,
                                              long long total) {
    long long t = (long long)blockIdx.x * 256 + threadIdx.x;
    long long base = t * 8;
    if (base >= total) return;
    int c = (int)(base & 127);
    float4 a = *(const float4*)&x[base];
    float4 b = *(const float4*)&x[base + 4];
    unsigned short u[8];
    u[0] = f2b(a.x * sigf[c + 0]); u[1] = f2b(a.y * sigf[c + 1]);
    u[2] = f2b(a.z * sigf[c + 2]); u[3] = f2b(a.w * sigf[c + 3]);
    u[4] = f2b(b.x * sigf[c + 4]); u[5] = f2b(b.y * sigf[c + 5]);
    u[6] = f2b(b.z * sigf[c + 6]); u[7] = f2b(b.w * sigf[c + 7]);
    *(uint4*)&xg[base] = *(uint4*)u;
}

// ---------- degree count, XCD-partitioned by node range ----------
// group g = blockIdx&7 (round-robins XCDs); owns nodes [g*n/8,(g+1)*n/8).
// Each group streams the full src array; atomics stay XCD-local.
#define EPB 4096  // edges per chunk (256 thr x 16)
__global__ __launch_bounds__(256) void k_deg2(const int* __restrict__ src,
                                              int* __restrict__ deg, int E, int n) {
    int g = blockIdx.x & 7;
    int chunk = blockIdx.x >> 3;
    int lo = (int)((long long)g * n >> 3);
    int hi = (int)((long long)(g + 1) * n >> 3);
    int base = chunk * EPB;
#pragma unroll
    for (int k = 0; k < 16; ++k) {
        int e = base + k * 256 + threadIdx.x;
        if (e < E) {
            int s = src[e];
            if (s >= lo && s < hi) atomicAdd(&deg[s], 1);
        }
    }
}

// ---------- scan (3 kernels) ----------
__global__ void k_scan1(const int* __restrict__ deg, int* __restrict__ bsum, int n) {
    __shared__ int lds[256];
    int i = blockIdx.x * 256 + threadIdx.x;
    lds[threadIdx.x] = (i < n) ? deg[i] : 0;
    __syncthreads();
    for (int s = 128; s > 0; s >>= 1) {
        if (threadIdx.x < s) lds[threadIdx.x] += lds[threadIdx.x + s];
        __syncthreads();
    }
    if (threadIdx.x == 0) bsum[blockIdx.x] = lds[0];
}

__global__ void k_scan2(const int* __restrict__ bsum, int* __restrict__ boff, int nb,
                        int* __restrict__ off, int n, int Etot) {
    __shared__ int lds[512];
    int t = threadIdx.x;
    int v = (t < nb) ? bsum[t] : 0;
    lds[t] = v;
    __syncthreads();
    for (int s = 1; s < 512; s <<= 1) {
        int add = (t >= s) ? lds[t - s] : 0;
        __syncthreads();
        lds[t] += add;
        __syncthreads();
    }
    if (t < nb) boff[t] = lds[t] - v;  // exclusive
    if (t == 0) off[n] = Etot;
}

__global__ void k_scan3(const int* __restrict__ deg, const int* __restrict__ boff,
                        int* __restrict__ off, int* __restrict__ pos, int n) {
    __shared__ int lds[256];
    int i = blockIdx.x * 256 + threadIdx.x;
    int v = (i < n) ? deg[i] : 0;
    lds[threadIdx.x] = v;
    __syncthreads();
    for (int s = 1; s < 256; s <<= 1) {
        int add = (threadIdx.x >= s) ? lds[threadIdx.x - s] : 0;
        __syncthreads();
        lds[threadIdx.x] += add;
        __syncthreads();
    }
    if (i < n) {
        int ex = boff[blockIdx.x] + lds[threadIdx.x] - v;
        off[i] = ex;
        pos[i] = ex;
    }
}

// ---------- CSR fill, XCD-partitioned by node range ----------
__global__ __launch_bounds__(256) void k_fill2(const int* __restrict__ src,
                                               const int* __restrict__ dst,
                                               int* __restrict__ pos, int* __restrict__ csr,
                                               int E, int n) {
    int g = blockIdx.x & 7;
    int chunk = blockIdx.x >> 3;
    int lo = (int)((long long)g * n >> 3);
    int hi = (int)((long long)(g + 1) * n >> 3);
    int base = chunk * EPB;
#pragma unroll
    for (int k = 0; k < 16; ++k) {
        int e = base + k * 256 + threadIdx.x;
        if (e < E) {
            int s = src[e];
            if (s >= lo && s < hi) {
                int p = atomicAdd(&pos[s], 1);
                csr[p] = dst[e];
            }
        }
    }
}

// ---------- aggregate (bf16 gather): mean_neighbor + dilution gate ----------
__global__ __launch_bounds__(256) void k_agg(
    const unsigned short* __restrict__ xg,
    const int* __restrict__ off, const int* __restrict__ csr,
    const float* __restrict__ gw, const float* __restrict__ gb,
    unsigned short* __restrict__ meanb, float* __restrict__ gate, int n) {
    int wave = (blockIdx.x * blockDim.x + threadIdx.x) >> 6;
    int lane = threadIdx.x & 63;
    if (wave >= n) return;
    int i = wave;
    int c0 = lane * 2;
    int beg = off[i], end = off[i + 1];
    float s0 = 0.f, s1 = 0.f;
    int e = beg;
    for (; e + 4 <= end; e += 4) {
        int d0 = csr[e], d1 = csr[e + 1], d2 = csr[e + 2], d3 = csr[e + 3];
        unsigned u0 = *(const unsigned*)&xg[(size_t)d0 * 128 + c0];
        unsigned u1 = *(const unsigned*)&xg[(size_t)d1 * 128 + c0];
        unsigned u2 = *(const unsigned*)&xg[(size_t)d2 * 128 + c0];
        unsigned u3 = *(const unsigned*)&xg[(size_t)d3 * 128 + c0];
        s0 += blo(u0) + blo(u1) + blo(u2) + blo(u3);
        s1 += bhi(u0) + bhi(u1) + bhi(u2) + bhi(u3);
    }
    for (; e < end; ++e) {
        int d = csr[e];
        unsigned u = *(const unsigned*)&xg[(size_t)d * 128 + c0];
        s0 += blo(u);
        s1 += bhi(u);
    }
    int dg = end - beg;
    float inv = 1.f / fmaxf((float)dg, 1.f);
    float m0 = s0 * inv, m1 = s1 * inv;
    unsigned packed = (unsigned)f2b(m0) | ((unsigned)f2b(m1) << 16);
    *(unsigned*)&meanb[(size_t)i * 128 + c0] = packed;
    unsigned ux = *(const unsigned*)&xg[(size_t)i * 128 + c0];
    float x0 = blo(ux), x1 = bhi(ux);
    float px = x0 * x0 + x1 * x1;
    float pm = m0 * m0 + m1 * m1;
    float pc = x0 * m0 + x1 * m1;
    for (int s = 32; s > 0; s >>= 1) {
        px += __shfl_xor(px, s, 64);
        pm += __shfl_xor(pm, s, 64);
        pc += __shfl_xor(pc, s, 64);
    }
    if (lane == 0) {
        float nx = fmaxf(sqrtf(px), 1e-12f), nm = fmaxf(sqrtf(pm), 1e-12f);
        float sim = pc / (nx * nm);
        if (dg <= 0) sim = 1.f;
        float delta = sigmoidf_((float)dg * (1.f - sim) * 0.1f - 0.5f);
        float g = sigmoidf_(gw[0] * delta + gb[0]);
        gate[i] = g;
    }
}

// ---------- MFMA GEMM: h = gate-combine([xg|mean] @ Wfull), fused BN stats ----------
__global__ __launch_bounds__(256) void k_gemm2(
    const unsigned short* __restrict__ xg, const unsigned short* __restrict__ meanb,
    const unsigned short* __restrict__ WfT,
    const float* __restrict__ b_mean, const float* __restrict__ b_ego,
    const float* __restrict__ b_nb, const float* __restrict__ gate,
    float* __restrict__ h, float* __restrict__ stats, int n) {
    int lane = threadIdx.x & 63;
    int w = threadIdx.x >> 6;
    int row0 = blockIdx.x * 64;
    int rl = lane & 15;
    int kg = lane >> 4;

    fx4 acc[4][4];
#pragma unroll
    for (int a = 0; a < 4; a++)
#pragma unroll
        for (int b = 0; b < 4; b++) acc[a][b] = (fx4){0.f, 0.f, 0.f, 0.f};

    int cb0 = 32 * w;
#pragma unroll
    for (int ks = 0; ks < 8; ++ks) {
        int k = ks * 32 + kg * 8;
        bfx8 af[4];
#pragma unroll
        for (int fa = 0; fa < 4; ++fa) {
            int grow = row0 + 16 * fa + rl;
            if (grow >= n) grow = n - 1;
            const unsigned short* src = (k < 128)
                ? &xg[(size_t)grow * 128 + k]
                : &meanb[(size_t)grow * 128 + (k - 128)];
            af[fa] = *(const bfx8*)src;
        }
        bfx8 bf[4];
#pragma unroll
        for (int fb = 0; fb < 4; ++fb) {
            int col = cb0 + 16 * (fb & 1) + 128 * (fb >> 1) + rl;
            bf[fb] = *(const bfx8*)&WfT[(size_t)col * 256 + k];
        }
#pragma unroll
        for (int fa = 0; fa < 4; ++fa)
#pragma unroll
            for (int fb = 0; fb < 4; ++fb)
                acc[fa][fb] = __builtin_amdgcn_mfma_f32_16x16x32_bf16(af[fa], bf[fb], acc[fa][fb], 0, 0, 0);
    }

    // epilogue: gate combine + h write + BN stats partials
    int j0 = cb0 + rl;
    int j1 = j0 + 16;
    float bm0 = b_mean[j0], bm1 = b_mean[j1];
    float bc0 = (j0 < 64) ? b_ego[j0] : b_nb[j0 - 64];
    float bc1 = (j1 < 64) ? b_ego[j1] : b_nb[j1 - 64];
    float cs0 = 0.f, cs1 = 0.f, cq0 = 0.f, cq1 = 0.f;
#pragma unroll
    for (int fa = 0; fa < 4; ++fa) {
#pragma unroll
        for (int r = 0; r < 4; ++r) {
            int grow = row0 + 16 * fa + 4 * kg + r;
            if (grow < n) {
                float g = gate[grow];
                float h0 = (1.f - g) * (acc[fa][0][r] + bm0) + g * (acc[fa][2][r] + bc0);
                float h1 = (1.f - g) * (acc[fa][1][r] + bm1) + g * (acc[fa][3][r] + bc1);
                h[(size_t)grow * 128 + j0] = h0;
                h[(size_t)grow * 128 + j1] = h1;
                cs0 += h0; cq0 += h0 * h0;
                cs1 += h1; cq1 += h1 * h1;
            }
        }
    }
    cs0 += __shfl_xor(cs0, 16, 64); cs0 += __shfl_xor(cs0, 32, 64);
    cq0 += __shfl_xor(cq0, 16, 64); cq0 += __shfl_xor(cq0, 32, 64);
    cs1 += __shfl_xor(cs1, 16, 64); cs1 += __shfl_xor(cs1, 32, 64);
    cq1 += __shfl_xor(cq1, 16, 64); cq1 += __shfl_xor(cq1, 32, 64);
    if (lane < 16) {
        atomicAdd(&stats[j0], cs0);
        atomicAdd(&stats[128 + j0], cq0);
        atomicAdd(&stats[j1], cs1);
        atomicAdd(&stats[128 + j1], cq1);
    }
}

// ---------- BN finalize ----------
__global__ void k_bnfin(const float* __restrict__ stats, const float* __restrict__ gamma,
                        const float* __restrict__ beta, float* __restrict__ sshift, int n) {
    int j = threadIdx.x;
    if (j < 128) {
        float invn = 1.f / (float)n;
        float mu = stats[j] * invn;
        float var = stats[128 + j] * invn - mu * mu;
        float rstd = 1.f / sqrtf(var + 1e-5f);
        float sc = gamma[j] * rstd;
        sshift[j] = sc;
        sshift[128 + j] = beta[j] - sc * mu;
    }
}

// ---------- normalize+relu+h@W_gcn fused, wave per row ----------
__global__ __launch_bounds__(256) void k_hw(
    const float* __restrict__ h, const float* __restrict__ sshift,
    const float* __restrict__ Wg, const int* __restrict__ deg,
    float* __restrict__ hw, float* __restrict__ dinv, int n) {
    int wave = (blockIdx.x * blockDim.x + threadIdx.x) >> 6;
    int lane = threadIdx.x & 63;
    if (wave >= n) return;
    int i = wave;
    int c0 = lane * 2;
    float2 hv = *(const float2*)&h[(size_t)i * 128 + c0];
    float h0 = fmaxf(hv.x * sshift[c0] + sshift[128 + c0], 0.f);
    float h1 = fmaxf(hv.y * sshift[c0 + 1] + sshift[128 + c0 + 1], 0.f);
    float p0 = h0 * Wg[c0 * 2 + 0] + h1 * Wg[(c0 + 1) * 2 + 0];
    float p1 = h0 * Wg[c0 * 2 + 1] + h1 * Wg[(c0 + 1) * 2 + 1];
    for (int s = 32; s > 0; s >>= 1) {
        p0 += __shfl_xor(p0, s, 64);
        p1 += __shfl_xor(p1, s, 64);
    }
    if (lane == 0) {
        hw[(size_t)i * 2 + 0] = p0;
        hw[(size_t)i * 2 + 1] = p1;
        dinv[i] = rsqrtf((float)(deg[i] + 1));
    }
}

// ---------- GCN scatter via CSR, 16 lanes per node ----------
__global__ __launch_bounds__(256) void k_out(
    const int* __restrict__ off, const int* __restrict__ csr,
    const float* __restrict__ dinv, const float* __restrict__ hw,
    const float* __restrict__ bg, float* __restrict__ out, int n) {
    int t = blockIdx.x * blockDim.x + threadIdx.x;
    int node = t >> 4;
    int l = t & 15;
    if (node >= n) return;
    float s0 = 0.f, s1 = 0.f;
    int beg = off[node], end = off[node + 1];
    for (int e = beg + l; e < end; e += 16) {
        int d = csr[e];
        float wgt = dinv[d];
        float2 hv = *(const float2*)&hw[(size_t)d * 2];
        s0 += wgt * hv.x;
        s1 += wgt * hv.y;
    }
    for (int m = 8; m > 0; m >>= 1) {
        s0 += __shfl_xor(s0, m, 16);
        s1 += __shfl_xor(s1, m, 16);
    }
    if (l == 0) {
        float di = dinv[node];
        float2 hv = *(const float2*)&hw[(size_t)node * 2];
        out[(size_t)node * 2 + 0] = bg[0] + di * (s0 + di * hv.x);
        out[(size_t)node * 2 + 1] = bg[1] + di * (s1 + di * hv.y);
    }
}

extern "C" void kernel_launch(void* const* d_in, const int* in_sizes, int n_in,
                              void* d_out, int out_size, void* d_ws, size_t ws_size,
                              hipStream_t stream) {
    const float* x     = (const float*)d_in[0];
    const int*   ei    = (const int*)d_in[1];
    const float* fi    = (const float*)d_in[2];
    const float* Wm    = (const float*)d_in[3];
    const float* bm    = (const float*)d_in[4];
    const float* We    = (const float*)d_in[5];
    const float* be    = (const float*)d_in[6];
    const float* Wn    = (const float*)d_in[7];
    const float* bn    = (const float*)d_in[8];
    const float* gw    = (const float*)d_in[9];
    const float* gb    = (const float*)d_in[10];
    const float* gamma = (const float*)d_in[11];
    const float* beta  = (const float*)d_in[12];
    const float* Wg    = (const float*)d_in[13];
    const float* bg    = (const float*)d_in[14];

    int n = in_sizes[0] / 128;
    int E = in_sizes[1] / 2;
    const int* src = ei;
    const int* dst = ei + E;

    char* p = (char*)d_ws;
    auto alloc = [&](size_t bytes) {
        void* r = (void*)p;
        p += (bytes + 255) & ~(size_t)255;
        return r;
    };
    unsigned short* xg    = (unsigned short*)alloc((size_t)n * 128 * 2);
    unsigned short* meanb = (unsigned short*)alloc((size_t)n * 128 * 2);
    float*          h     = (float*)alloc((size_t)n * 128 * 4);
    unsigned short* WfT   = (unsigned short*)alloc(256 * 256 * 2);
    int*   deg    = (int*)alloc((size_t)n * 4);
    int*   off    = (int*)alloc((size_t)(n + 1) * 4);
    int*   pos    = (int*)alloc((size_t)(n + 1) * 4);
    int*   csr    = (int*)alloc((size_t)E * 4);
    int*   bsum   = (int*)alloc(512 * 4);
    int*   boff   = (int*)alloc(512 * 4);
    float* gate   = (float*)alloc((size_t)n * 4);
    float* stats  = (float*)alloc(256 * 4);
    float* sshift = (float*)alloc(256 * 4);
    float* dinv   = (float*)alloc((size_t)n * 4);
    float* hwbuf  = (float*)alloc((size_t)n * 2 * 4);
    float* sigf   = (float*)alloc(128 * 4);

    hipMemsetAsync(deg, 0, (size_t)n * 4, stream);
    hipMemsetAsync(stats, 0, 256 * 4, stream);

    k_prep<<<1, 128, 0, stream>>>(fi, sigf);
    k_wfullT<<<256, 256, 0, stream>>>(Wm, We, Wn, WfT);

    long long total = (long long)n * 128;
    int convBlocks = (int)((total / 8 + 255) / 256);
    k_conv<<<convBlocks, 256, 0, stream>>>(x, sigf, xg, total);

    int nchunks = (E + EPB - 1) / EPB;
    k_deg2<<<nchunks * 8, 256, 0, stream>>>(src, deg, E, n);

    int nb = (n + 255) / 256;
    k_scan1<<<nb, 256, 0, stream>>>(deg, bsum, n);
    k_scan2<<<1, 512, 0, stream>>>(bsum, boff, nb, off, n, E);
    k_scan3<<<nb, 256, 0, stream>>>(deg, boff, off, pos, n);
    k_fill2<<<nchunks * 8, 256, 0, stream>>>(src, dst, pos, csr, E, n);

    k_agg<<<(n + 3) / 4, 256, 0, stream>>>(xg, off, csr, gw, gb, meanb, gate, n);
    k_gemm2<<<(n + 63) / 64, 256, 0, stream>>>(xg, meanb, WfT, bm, be, bn, gate, h, stats, n);
    k_bnfin<<<1, 128, 0, stream>>>(stats, gamma, beta, sshift, n);
    k_hw<<<(n + 3) / 4, 256, 0, stream>>>(h, sshift, Wg, deg, hwbuf, dinv, n);
    k_out<<<(n + 15) / 16, 256, 0, stream>>>(off, csr, dinv, hwbuf, bg, (float*)d_out, n);
}